// Round 9
// baseline (286.091 us; speedup 1.0000x reference)
//
#include <hip/hip_runtime.h>

#define NEMBD 2048
#define ROW4 (NEMBD / 4)    // 512 float4 per token row
#define NEXP 8
#define W4N (NEXP * ROW4)   // 4096 float4 = 64 KB

// Block = 512 threads = 8 waves. W (64 KB) staged once per block in LDS
// -> 2 blocks/CU co-resident (128 KB of 160 KB), so one block's compute
// overlaps the other's loads. One wave = 2 consecutive tokens.
// x rows are preloaded into registers in two 4-chunk halves for ILP:
// half A issues before W staging (latency hides under stage+barrier),
// half B issues after the barrier (hides under half A's FMA burst).
__global__ __launch_bounds__(512) void gate_kernel(
    const float* __restrict__ x, const float* __restrict__ W,
    float* __restrict__ out, float* __restrict__ ws, int ntok)
{
    __shared__ float4 Wl[W4N];          // exactly 64 KB

    const int tid  = threadIdx.x;
    const int lane = tid & 63;
    const int wid  = tid >> 6;          // 0..7

    const float4* X4 = (const float4*)x;
    const float4* W4 = (const float4*)W;

    const int t0 = blockIdx.x * 16 + wid * 2;   // this wave's first token
    const bool va0 = t0 < ntok, va1 = (t0 + 1) < ntok;
    const float4 z4 = make_float4(0.f, 0.f, 0.f, 0.f);

    // Issue first-half x loads (chunks 0..3): 16 loads in flight.
    float4 xa0[4], xa1[4];
    #pragma unroll
    for (int i = 0; i < 4; ++i) {
        const int col = i * 64 + lane;
        xa0[i] = va0 ? X4[(size_t)t0 * ROW4 + col] : z4;
        xa1[i] = va1 ? X4[(size_t)(t0 + 1) * ROW4 + col] : z4;
    }

    // Stage W into LDS (512 thr x 8 float4) while x loads are in flight.
    #pragma unroll
    for (int k = 0; k < 8; ++k)
        Wl[tid + k * 512] = W4[tid + k * 512];
    __syncthreads();

    // Issue second-half x loads (chunks 4..7); they return under the
    // first half's compute below.
    float4 xb0[4], xb1[4];
    #pragma unroll
    for (int i = 0; i < 4; ++i) {
        const int col = (i + 4) * 64 + lane;
        xb0[i] = va0 ? X4[(size_t)t0 * ROW4 + col] : z4;
        xb1[i] = va1 ? X4[(size_t)(t0 + 1) * ROW4 + col] : z4;
    }

    float a[16];
    #pragma unroll
    for (int q = 0; q < 16; ++q) a[q] = 0.f;

    // Compute: pure ds_read_b128 + FMA, no global loads, static indices.
    #pragma unroll
    for (int i = 0; i < 4; ++i) {
        const int col = i * 64 + lane;
        #pragma unroll
        for (int e = 0; e < 8; ++e) {
            float4 wv = Wl[e * ROW4 + col];
            a[e]     += xa0[i].x * wv.x + xa0[i].y * wv.y
                      + xa0[i].z * wv.z + xa0[i].w * wv.w;
            a[8 + e] += xa1[i].x * wv.x + xa1[i].y * wv.y
                      + xa1[i].z * wv.z + xa1[i].w * wv.w;
        }
    }
    #pragma unroll
    for (int i = 0; i < 4; ++i) {
        const int col = (i + 4) * 64 + lane;
        #pragma unroll
        for (int e = 0; e < 8; ++e) {
            float4 wv = Wl[e * ROW4 + col];
            a[e]     += xb0[i].x * wv.x + xb0[i].y * wv.y
                      + xb0[i].z * wv.z + xb0[i].w * wv.w;
            a[8 + e] += xb1[i].x * wv.x + xb1[i].y * wv.y
                      + xb1[i].z * wv.z + xb1[i].w * wv.w;
        }
    }

    // Reduce across lanes. Two pure butterfly steps collapse the 4 lanes
    // sharing (lane mod 16); four split steps distribute so lane l holds
    // the full logit for accumulator index (l & 15):
    //   token t0 + ((l>>3)&1), expert (l&7).  (16-lane groups replicate.)
    #pragma unroll
    for (int q = 0; q < 16; ++q) a[q] += __shfl_xor(a[q], 32, 64);
    #pragma unroll
    for (int q = 0; q < 16; ++q) a[q] += __shfl_xor(a[q], 16, 64);
    #pragma unroll
    for (int s = 0; s < 4; ++s) {
        const int hm = 8 >> s;
        const bool hi = (lane & hm) != 0;
        #pragma unroll
        for (int q = 0; q < 8; ++q) {
            if (q < hm) {
                float send = hi ? a[q] : a[q + hm];
                float recv = __shfl_xor(send, hm, 64);
                float keep = hi ? a[q + hm] : a[q];
                a[q] = keep + recv;
            }
        }
    }
    const float logit = a[0];
    const int e = lane & 7;
    const int k = (lane >> 3) & 1;
    const bool tvalid = (t0 + k) < ntok;

    float* out_p = out;             // [ntok][2] renormalized top-2 probs
    float* out_i = out + 2 * ntok;  // [ntok][2] indices (as float)

    // Softmax across the 8-lane expert group.
    float m = logit;
    #pragma unroll
    for (int mm = 1; mm <= 4; mm <<= 1) m = fmaxf(m, __shfl_xor(m, mm, 64));
    float p = __expf(logit - m);
    float ssum = p;
    #pragma unroll
    for (int mm = 1; mm <= 4; mm <<= 1) ssum += __shfl_xor(ssum, mm, 64);
    const float prob = p / ssum;

    // Top-2 butterfly merge (lower index wins ties — matches jax.lax.top_k
    // / argmax first-occurrence semantics).
    float v1 = prob, v2 = -1.f;
    int   i1 = e,    i2 = -1;
    #pragma unroll
    for (int mm = 1; mm <= 4; mm <<= 1) {
        float b1 = __shfl_xor(v1, mm, 64);
        float b2 = __shfl_xor(v2, mm, 64);
        int  bi1 = __shfl_xor(i1, mm, 64);
        int  bi2 = __shfl_xor(i2, mm, 64);
        bool aw = (v1 > b1) || (v1 == b1 && i1 < bi1);
        float w1 = aw ? v1 : b1;  int wi1 = aw ? i1 : bi1;
        float l1 = aw ? b1 : v1;  int li1 = aw ? bi1 : i1;
        float w2 = aw ? v2 : b2;  int wi2 = aw ? i2 : bi2;
        bool sw = (l1 > w2) || (l1 == w2 && li1 < wi2);
        v1 = w1; i1 = wi1;
        v2 = sw ? l1 : w2;  i2 = sw ? li1 : wi2;
    }

    if (e == 0 && lane < 16 && tvalid) {
        const int t = t0 + k;
        const float denom = v1 + v2;
        out_p[2 * t]     = v1 / denom;
        out_p[2 * t + 1] = v2 / denom;
        out_i[2 * t]     = (float)i1;
        out_i[2 * t + 1] = (float)i2;
    }

    // Aux-loss partials. Sum over the wave's 2 tokens (xor 8): lanes l and
    // l^8 both end with the per-expert (l&7) sums.
    float pc = tvalid ? prob : 0.f;
    float oc = (tvalid && e == i1) ? 1.f : 0.f;
    pc += __shfl_xor(pc, 8, 64);
    oc += __shfl_xor(oc, 8, 64);

    // Reuse the W LDS region for per-wave partials (W reads are all done).
    float* part = (float*)Wl;           // [8 waves][16]
    __syncthreads();                    // last W read before overwrite
    if (lane < 8)       part[wid * 16 + lane] = pc;        // imp[e]
    else if (lane < 16) part[wid * 16 + lane] = oc;        // load[e] at +8
    __syncthreads();
    if (tid < 16) {
        float v = 0.f;
        #pragma unroll
        for (int w = 0; w < 8; ++w) v += part[w * 16 + tid];
        ws[blockIdx.x * 16 + tid] = v;
    }
}

__global__ void finalize_kernel(const float* __restrict__ ws,
                                float* __restrict__ out, int nblk, int ntok)
{
    __shared__ float s[16][16];
    __shared__ float tot[16];
    const int t = threadIdx.x;
    const int slot = t & 15, chunk = t >> 4;
    float p = 0.f;
    for (int b = chunk; b < nblk; b += 16) p += ws[b * 16 + slot];
    s[chunk][slot] = p;
    __syncthreads();
    if (t < 16) {
        float v = 0.f;
        #pragma unroll
        for (int c = 0; c < 16; ++c) v += s[c][t];
        tot[t] = v;
    }
    __syncthreads();
    if (t == 0) {
        const float inv = 1.f / (float)ntok;
        float aux = 0.f;
        #pragma unroll
        for (int e = 0; e < 8; ++e)
            aux += (tot[e] * inv) * (tot[8 + e] * inv);
        out[4 * ntok] = 8.f * aux * 0.01f;
    }
}

extern "C" void kernel_launch(void* const* d_in, const int* in_sizes, int n_in,
                              void* d_out, int out_size, void* d_ws, size_t ws_size,
                              hipStream_t stream)
{
    const float* x = (const float*)d_in[0];
    const float* W = (const float*)d_in[1];
    const int ntok    = in_sizes[0] / NEMBD;    // 16384
    const int nblocks = (ntok + 15) / 16;       // 1024 blocks x 8 waves

    gate_kernel<<<nblocks, 512, 0, stream>>>(
        x, W, (float*)d_out, (float*)d_ws, ntok);
    finalize_kernel<<<1, 256, 0, stream>>>(
        (const float*)d_ws, (float*)d_out, nblocks, ntok);
}